// Round 8
// baseline (486.095 us; speedup 1.0000x reference)
//
#include <hip/hip_runtime.h>

typedef unsigned short u16;
typedef unsigned int u32;

constexpr int H_ = 64;
constexpr int W_ = 256;
constexpr int HW_ = H_ * W_;

typedef __bf16 bf16x8 __attribute__((ext_vector_type(8)));
typedef float f32x4 __attribute__((ext_vector_type(4)));

__device__ __forceinline__ float bf2f(u16 v) { return __uint_as_float(((u32)v) << 16); }
__device__ __forceinline__ u16 f2bf(float f) {
  u32 x = __float_as_uint(f);
  u32 r = (x + 0x7fffu + ((x >> 16) & 1u)) >> 16;
  return (u16)r;
}
__device__ __forceinline__ float lo2f(u32 p) { return __uint_as_float(p << 16); }
__device__ __forceinline__ float hi2f(u32 p) { return __uint_as_float(p & 0xffff0000u); }
__device__ __forceinline__ void unpack8(uint4 v, float* f) {
  f[0] = lo2f(v.x); f[1] = hi2f(v.x);
  f[2] = lo2f(v.y); f[3] = hi2f(v.y);
  f[4] = lo2f(v.z); f[5] = hi2f(v.z);
  f[6] = lo2f(v.w); f[7] = hi2f(v.w);
}
__device__ __forceinline__ bf16x8 as_bf16x8(uint4 v) {
  union { uint4 u; bf16x8 b; } x; x.u = v; return x.b;
}
// bank swizzle: channel c of position p lives at column c ^ (((p>>3)&3)<<3).
__device__ __forceinline__ int swz(int p, int c) { return c ^ (((p >> 3) & 3) << 3); }

// ---------------- normalize all f32 inputs to a bf16 arena ----------------
constexpr int NT = 26;
constexpr int ELEMS_PER_BLK = 4096;
struct CvtArgs {
  const void* src[NT];
  u32 dst_off[NT];
  u32 n[NT];
  u32 blk_start[NT];
};

__global__ void convert_all(CvtArgs a, u16* __restrict__ dst) {
  const u32 bid = blockIdx.x;
  int ti = 0;
#pragma unroll
  for (int k = 1; k < NT; ++k) if (a.blk_start[k] <= bid) ti = k;
  const u32 e0 = (bid - a.blk_start[ti]) * ELEMS_PER_BLK;
  const u32 n = a.n[ti];
  u32 hi = e0 + ELEMS_PER_BLK; if (hi > n) hi = n;
  const float* sp = (const float*)a.src[ti];
  u16* d = dst + a.dst_off[ti];
  for (u32 i = e0 + threadIdx.x; i < hi; i += 256) d[i] = f2bf(sp[i]);
}

// ---------------- MFMA 1x1-conv GEMM ----------------
// RES: 0 none, 2 bf16 single, 3 f32 single, 4 f32 dual (cat batch)
template <int CIN, int COUT, int POS, int NOG, bool LN, bool SILU, bool IN_F32, int RES, bool OUT_F32>
__launch_bounds__(256)
__global__ void gemm1x1_mfma(const void* __restrict__ xA, const void* __restrict__ xB,
                             const u16* __restrict__ w, const u16* __restrict__ bias,
                             const u16* __restrict__ lng, const u16* __restrict__ lnb,
                             float lneps,
                             const void* __restrict__ resA, const void* __restrict__ resB,
                             void* __restrict__ out, int b_off) {
  static_assert(!LN || (CIN == 128 && POS == 64), "LN path assumes CIN=128, POS=64");
  constexpr int PITCH = CIN + 8;
  constexpr int MT = COUT / NOG / 64;
  constexpr int NTL = POS / 16;
  __shared__ __align__(16) u16 xs[POS * PITCH];
  const int t = threadIdx.x;
  const int b = blockIdx.y;
  const int bo2 = b + b_off;
  const int pos0 = blockIdx.x * POS;
  const int og0 = blockIdx.z * (COUT / NOG);

  const u16* xb16 = nullptr;
  const float* xf32 = nullptr;
  if constexpr (IN_F32) {
    xf32 = ((const float*)xA) + (size_t)b * CIN * HW_;
  } else {
    const u16* basep = (const u16*)((xB != nullptr && b >= 2) ? xB : xA);
    const int bb = (xB != nullptr) ? ((b < 2) ? b : b - 2) : b;
    xb16 = basep + (size_t)bb * CIN * HW_;
  }

  if constexpr (IN_F32) {
    constexpr int NLOAD = CIN * POS / 4;
    for (int idx = t; idx < NLOAD; idx += 256) {
      const int c = idx / (POS / 4);
      const int p4 = (idx % (POS / 4)) * 4;
      float4 v = *(const float4*)(xf32 + (size_t)c * HW_ + pos0 + p4);
      const int csw = swz(p4, c);
      u16* row = xs + p4 * PITCH + csw;
      row[0]         = f2bf(v.x);
      row[PITCH]     = f2bf(v.y);
      row[2 * PITCH] = f2bf(v.z);
      row[3 * PITCH] = f2bf(v.w);
    }
  } else {
    constexpr int NLOAD = CIN * POS / 8;
    for (int idx = t; idx < NLOAD; idx += 256) {
      const int c = idx / (POS / 8);
      const int p8 = (idx % (POS / 8)) * 8;
      uint4 v = *(const uint4*)(xb16 + (size_t)c * HW_ + pos0 + p8);
      const int csw = swz(p8, c);
      u16* row = xs + p8 * PITCH + csw;
      row[0]         = (u16)v.x; row[PITCH]     = (u16)(v.x >> 16);
      row[2 * PITCH] = (u16)v.y; row[3 * PITCH] = (u16)(v.y >> 16);
      row[4 * PITCH] = (u16)v.z; row[5 * PITCH] = (u16)(v.z >> 16);
      row[6 * PITCH] = (u16)v.w; row[7 * PITCH] = (u16)(v.w >> 16);
    }
  }
  __syncthreads();

  if constexpr (LN) {
    __shared__ float red1[256], red2[256], stm[64], str[64];
    const int p = t & 63, part = t >> 6;
    const int xorp = ((p >> 3) & 3) << 3;
    float s = 0.f, sq = 0.f;
#pragma unroll
    for (int k = 0; k < 32; k += 8) {
      uint4 v = *(const uint4*)(xs + p * PITCH + ((part * 32 + k) ^ xorp));
      float f[8]; unpack8(v, f);
#pragma unroll
      for (int j = 0; j < 8; ++j) { s += f[j]; sq += f[j] * f[j]; }
    }
    red1[part * 64 + p] = s; red2[part * 64 + p] = sq;
    __syncthreads();
    if (t < 64) {
      float ss = red1[t] + red1[64 + t] + red1[128 + t] + red1[192 + t];
      float qq = red2[t] + red2[64 + t] + red2[128 + t] + red2[192 + t];
      float m = ss * (1.0f / CIN);
      float var = qq * (1.0f / CIN) - m * m;
      var = var < 0.f ? 0.f : var;
      stm[t] = m; str[t] = rsqrtf(var + lneps);
    }
    __syncthreads();
    const float m = stm[p], r = str[p];
#pragma unroll
    for (int k = 0; k < 32; k += 8) {
      const int c = part * 32 + k;
      uint4 v = *(const uint4*)(xs + p * PITCH + (c ^ xorp));
      float f[8]; unpack8(v, f);
      u32 pk[4];
#pragma unroll
      for (int j = 0; j < 8; j += 2) {
        float g0 = bf2f(lng[c + j]), be0 = bf2f(lnb[c + j]);
        float g1 = bf2f(lng[c + j + 1]), be1 = bf2f(lnb[c + j + 1]);
        u16 lo = f2bf((f[j] - m) * r * g0 + be0);
        u16 hi = f2bf((f[j + 1] - m) * r * g1 + be1);
        pk[j >> 1] = (u32)lo | ((u32)hi << 16);
      }
      uint4 ov; ov.x = pk[0]; ov.y = pk[1]; ov.z = pk[2]; ov.w = pk[3];
      *(uint4*)(xs + p * PITCH + (c ^ xorp)) = ov;
    }
    __syncthreads();
  }

  const int lane = t & 63, wv = t >> 6;
  const int lo16 = lane & 15, quad = lane >> 4;
  const int orow0 = og0 + wv * MT * 16;
  const int qrow = quad * 4;

  f32x4 acc[MT][NTL];
#pragma unroll
  for (int mt = 0; mt < MT; ++mt) {
#pragma unroll
    for (int r = 0; r < 4; ++r) {
      const float bv = bf2f(bias[orow0 + mt * 16 + qrow + r]);
#pragma unroll
      for (int nt = 0; nt < NTL; ++nt) acc[mt][nt][r] = bv;
    }
  }

  const u16* xb[NTL];
#pragma unroll
  for (int nt = 0; nt < NTL; ++nt) {
    const int row = nt * 16 + lo16;
    xb[nt] = xs + row * PITCH + (quad * 8 ^ ((((row >> 3) & 3)) << 3));
  }
  const u16* wl = w + (size_t)(orow0 + lo16) * CIN + quad * 8;

#pragma unroll 2
  for (int kc = 0; kc < CIN / 32; ++kc) {
    const int c0 = kc * 32;
    bf16x8 bfr[NTL];
#pragma unroll
    for (int nt = 0; nt < NTL; ++nt)
      bfr[nt] = as_bf16x8(*(const uint4*)(xb[nt] + c0));
#pragma unroll
    for (int mt = 0; mt < MT; ++mt) {
      bf16x8 afr = as_bf16x8(*(const uint4*)(wl + (size_t)mt * 16 * CIN + c0));
#pragma unroll
      for (int nt = 0; nt < NTL; ++nt)
        acc[mt][nt] = __builtin_amdgcn_mfma_f32_16x16x32_bf16(afr, bfr[nt], acc[mt][nt], 0, 0, 0);
    }
  }

#pragma unroll
  for (int mt = 0; mt < MT; ++mt) {
#pragma unroll
    for (int nt = 0; nt < NTL; ++nt) {
#pragma unroll
      for (int r = 0; r < 4; ++r) {
        const int o = orow0 + mt * 16 + qrow + r;
        const int p = pos0 + nt * 16 + lo16;
        float v = acc[mt][nt][r];
        if constexpr (SILU) v = v / (1.0f + __expf(-v));
        const size_t gidx = ((size_t)bo2 * COUT + o) * HW_ + p;
        if constexpr (RES == 2) {
          v += bf2f(((const u16*)resA)[gidx]);
        } else if constexpr (RES == 3) {
          v += ((const float*)resA)[gidx];
        } else if constexpr (RES == 4) {
          const int bl = (bo2 < 2) ? bo2 : bo2 - 2;
          const float* rb = (bo2 < 2) ? (const float*)resA : (const float*)resB;
          v += rb[((size_t)bl * COUT + o) * HW_ + p];
        }
        if constexpr (OUT_F32) ((float*)out)[gidx] = v;
        else                   ((u16*)out)[gidx] = f2bf(v);
      }
    }
  }
}

// ---------------- MFMA attention ----------------
// LDS 69.5KB (2 blocks/CU): kT + vT + PlO (P during loop, O at end).
// Q A-frags straight from global; no max-subtraction (scores are tiny);
// O accumulated in registers across all 4 i-tiles.
__launch_bounds__(256)
__global__ void attn_mfma(const u16* __restrict__ qb, const u16* __restrict__ kvb,
                          u16* __restrict__ ob) {
  constexpr int PA = 40;    // kT/O pitch
  constexpr int PJ = 264;   // vT/P pitch
  __shared__ __align__(16) u16 kT[256 * PA];
  __shared__ __align__(16) u16 vT[32 * PJ];
  __shared__ __align__(16) u16 PlO[4 * 16 * PJ];  // P while looping; O after barrier
  const int t = threadIdx.x;
  const int h = blockIdx.x, n = blockIdx.y, b = blockIdx.z;
  const size_t qbase = ((size_t)(b * 128 + n * 32)) * HW_ + (size_t)h * W_;
  const size_t kbase = ((size_t)(b * 256 + n * 32)) * HW_ + (size_t)h * W_;
  const size_t vbase = ((size_t)(b * 256 + 128 + n * 32)) * HW_ + (size_t)h * W_;

#pragma unroll
  for (int d8 = 0; d8 < 4; ++d8) {
    u32 pk[4];
#pragma unroll
    for (int j = 0; j < 4; ++j) {
      u32 lo = kvb[kbase + (size_t)(d8 * 8 + 2 * j) * HW_ + t];
      u32 hi = kvb[kbase + (size_t)(d8 * 8 + 2 * j + 1) * HW_ + t];
      pk[j] = lo | (hi << 16);
    }
    *(uint4*)(kT + t * PA + d8 * 8) = make_uint4(pk[0], pk[1], pk[2], pk[3]);
  }
#pragma unroll
  for (int k = 0; k < 16; ++k) {
    const int idx = k * 256 + t;
    const int d = idx >> 7, p2 = (idx & 127) * 2;
    u32 v = *(const u32*)(kvb + vbase + (size_t)d * HW_ + p2);
    *(u32*)(vT + d * PJ + p2) = v;
  }
  __syncthreads();

  const int lane = t & 63, wv = t >> 6;
  const int lo16 = lane & 15, quad = lane >> 4;
  const float scale = 0.17677669529663687f;  // 32^-0.5
  const float renorm = 1.0f / (1.0f + 256.0f * 1e-6f);
  u16* Pw = PlO + wv * 16 * PJ;

  f32x4 oacc[4][2];
  for (int ii = 0; ii < 4; ++ii) {
    const int i0 = ii * 64 + wv * 16;
    // Q A-frag from global: A[m=lo16][k=quad*8+j] = q[d=quad*8+j][i0+lo16]
    u16 qr[8];
#pragma unroll
    for (int j = 0; j < 8; ++j)
      qr[j] = qb[qbase + (size_t)(quad * 8 + j) * HW_ + i0 + lo16];
    bf16x8 qa;
#pragma unroll
    for (int j = 0; j < 8; ++j) qa[j] = __uint_as_float(0) , qa[j] = *(__bf16*)&qr[j];
    f32x4 s[16];
#pragma unroll
    for (int jt = 0; jt < 16; ++jt) {
      bf16x8 kb = as_bf16x8(*(const uint4*)(kT + (jt * 16 + lo16) * PA + quad * 8));
      f32x4 z = {0.f, 0.f, 0.f, 0.f};
      s[jt] = __builtin_amdgcn_mfma_f32_16x16x32_bf16(qa, kb, z, 0, 0, 0);
    }
    // softmax, no max-subtraction (scores bounded); sum over j only
#pragma unroll
    for (int r = 0; r < 4; ++r) {
      float sum = 0.f;
#pragma unroll
      for (int jt = 0; jt < 16; ++jt) {
        float e = __expf(s[jt][r] * scale);
        s[jt][r] = e; sum += e;
      }
#pragma unroll
      for (int off = 1; off <= 8; off <<= 1) sum += __shfl_xor(sum, off, 64);
      const float inv = 1.0f / sum;
#pragma unroll
      for (int jt = 0; jt < 16; ++jt)
        Pw[(quad * 4 + r) * PJ + jt * 16 + lo16] = f2bf((s[jt][r] * inv + 1e-6f) * renorm);
    }
    f32x4 o0 = {0.f, 0.f, 0.f, 0.f}, o1 = {0.f, 0.f, 0.f, 0.f};
#pragma unroll
    for (int kt = 0; kt < 8; ++kt) {
      bf16x8 pa = as_bf16x8(*(const uint4*)(Pw + lo16 * PJ + kt * 32 + quad * 8));
      bf16x8 v0 = as_bf16x8(*(const uint4*)(vT + lo16 * PJ + kt * 32 + quad * 8));
      bf16x8 v1 = as_bf16x8(*(const uint4*)(vT + (16 + lo16) * PJ + kt * 32 + quad * 8));
      o0 = __builtin_amdgcn_mfma_f32_16x16x32_bf16(pa, v0, o0, 0, 0, 0);
      o1 = __builtin_amdgcn_mfma_f32_16x16x32_bf16(pa, v1, o1, 0, 0, 0);
    }
    oacc[ii][0] = o0; oacc[ii][1] = o1;
  }
  __syncthreads();          // all waves done with P
  u16* Ob = PlO;            // O[i][d], pitch PA
#pragma unroll
  for (int ii = 0; ii < 4; ++ii) {
    const int i0 = ii * 64 + wv * 16;
#pragma unroll
    for (int r = 0; r < 4; ++r) {
      Ob[(i0 + quad * 4 + r) * PA + lo16] = f2bf(oacc[ii][0][r]);
      Ob[(i0 + quad * 4 + r) * PA + 16 + lo16] = f2bf(oacc[ii][1][r]);
    }
  }
  __syncthreads();
  for (int d = 0; d < 32; ++d) ob[qbase + (size_t)d * HW_ + t] = Ob[t * PA + d];
}

// ---------------- fused depthwise 3/5/7, single batch ----------------
__launch_bounds__(256)
__global__ void dwconv_kernel(const u16* __restrict__ yB,
                              const u16* __restrict__ w3, const u16* __restrict__ b3,
                              const u16* __restrict__ w5, const u16* __restrict__ b5,
                              const u16* __restrict__ w7, const u16* __restrict__ b7,
                              u16* __restrict__ fB) {
  constexpr int LW = 70, LH = 14, LP = 72;
  __shared__ u16 tile[LH * LP];
  __shared__ float wf7[49], wf5[25], wf3[9];
  const int t = threadIdx.x;
  const int c = blockIdx.y;
  const int tw = blockIdx.x & 3, th = blockIdx.x >> 2;
  const int w0 = tw * 64, h0 = th * 8;
  const u16* src = yB + (size_t)c * HW_;

  if (t < 49) wf7[t] = bf2f(w7[c * 49 + t]);
  if (t >= 64 && t < 89) wf5[t - 64] = bf2f(w5[c * 25 + (t - 64)]);
  if (t >= 96 && t < 105) wf3[t - 96] = bf2f(w3[c * 9 + (t - 96)]);

  for (int idx = t; idx < LH * LW; idx += 256) {
    const int r = idx / LW, cc = idx - r * LW;
    const int gh = h0 + r - 3, gw = w0 + cc - 3;
    u16 v = 0;
    if (gh >= 0 && gh < H_ && gw >= 0 && gw < W_) v = src[gh * W_ + gw];
    tile[r * LP + cc] = v;
  }
  __syncthreads();

  const int x0 = (t & 31) * 2;
  const int hh = t >> 5;
  float a3x = 0.f, a3y = 0.f, a5x = 0.f, a5y = 0.f, a7x = 0.f, a7y = 0.f;
#pragma unroll
  for (int rr = 0; rr < 7; ++rr) {
    const u16* trow = tile + (hh + rr) * LP + x0;
    float f[10];
#pragma unroll
    for (int k = 0; k < 5; ++k) {
      u32 v = *(const u32*)(trow + 2 * k);
      f[2 * k] = lo2f(v); f[2 * k + 1] = hi2f(v);
    }
#pragma unroll
    for (int dx = 0; dx < 7; ++dx) {
      const float wv = wf7[rr * 7 + dx];
      a7x += wv * f[dx]; a7y += wv * f[dx + 1];
    }
    if (rr >= 1 && rr <= 5) {
#pragma unroll
      for (int dx = 0; dx < 5; ++dx) {
        const float wv = wf5[(rr - 1) * 5 + dx];
        a5x += wv * f[dx + 1]; a5y += wv * f[dx + 2];
      }
    }
    if (rr >= 2 && rr <= 4) {
#pragma unroll
      for (int dx = 0; dx < 3; ++dx) {
        const float wv = wf3[(rr - 2) * 3 + dx];
        a3x += wv * f[dx + 2]; a3y += wv * f[dx + 3];
      }
    }
  }
  const float B3v = bf2f(b3[c]), B5v = bf2f(b5[c]), B7v = bf2f(b7[c]);
  const size_t o0 = (size_t)c * HW_ + (size_t)(h0 + hh) * W_ + (w0 + x0);
  *(u32*)(fB + o0) = (u32)f2bf(a3x + B3v) | ((u32)f2bf(a3y + B3v) << 16);
  *(u32*)(fB + o0 + (size_t)256 * HW_) = (u32)f2bf(a5x + B5v) | ((u32)f2bf(a5y + B5v) << 16);
  *(u32*)(fB + o0 + (size_t)512 * HW_) = (u32)f2bf(a7x + B7v) | ((u32)f2bf(a7y + B7v) << 16);
}

extern "C" void kernel_launch(void* const* d_in, const int* in_sizes, int n_in,
                              void* d_out, int out_size, void* d_ws, size_t ws_size,
                              hipStream_t stream) {
  (void)out_size; (void)ws_size; (void)n_in;
  char* ws = (char*)d_ws;
  const size_t MB = 1ull << 20;

  u16* arena = (u16*)ws;
  CvtArgs ca;
  u32 off = 0, blk = 0;
  u32 aoff[NT];
  for (int i = 0; i < NT; ++i) {
    ca.src[i] = d_in[i];
    ca.n[i] = (u32)in_sizes[i];
    ca.dst_off[i] = off;
    aoff[i] = off;
    ca.blk_start[i] = blk;
    off += (ca.n[i] + 15u) & ~15u;
    blk += (ca.n[i] + ELEMS_PER_BLK - 1) / ELEMS_PER_BLK;
  }
  const u32 total_blocks = blk;

  const u16* f1c   = arena + aoff[0];
  const u16* f2c   = arena + aoff[1];
  const u16* an_g  = arena + aoff[2];
  const u16* an_b  = arena + aoff[3];
  const u16* anc_g = arena + aoff[4];
  const u16* anc_b = arena + aoff[5];
  const u16* wq    = arena + aoff[6];
  const u16* bq    = arena + aoff[7];
  const u16* wkv   = arena + aoff[8];
  const u16* bkv   = arena + aoff[9];
  const u16* wo    = arena + aoff[10];
  const u16* bo    = arena + aoff[11];
  const u16* fn_g  = arena + aoff[12];
  const u16* fn_b  = arena + aoff[13];
  const u16* w_in  = arena + aoff[14];
  const u16* b_in  = arena + aoff[15];
  const u16* w3    = arena + aoff[16];
  const u16* b3    = arena + aoff[17];
  const u16* w5    = arena + aoff[18];
  const u16* b5    = arena + aoff[19];
  const u16* w7    = arena + aoff[20];
  const u16* b7    = arena + aoff[21];
  const u16* w_pw  = arena + aoff[22];
  const u16* b_pw  = arena + aoff[23];
  const u16* w_out = arena + aoff[24];
  const u16* b_out = arena + aoff[25];

  float* cat1r = (float*)(ws + 24 * MB);   // [24,56)  f32, K4 -> K5,K8
  u16* qb      = (u16*)(ws + 56 * MB);     // [56,72)  K1 -> K3
  u16* kvb     = (u16*)(ws + 72 * MB);     // [72,104) K2 -> K3
  u16* obf     = (u16*)(ws + 104 * MB);    // [104,120) K3 -> K4
  u16* yb      = (u16*)(ws + 56 * MB);     // [56,88)  K5 -> K6,K7
  u16* fbuf_b  = (u16*)(ws + 88 * MB);     // [88,114) per-batch (25.17MB)
  u16* y2b     = (u16*)(ws + 114 * MB);    // [114,146) K7 -> K8
  float* outp  = (float*)d_out;

  dim3 blk256(256);
  convert_all<<<total_blocks, 256, 0, stream>>>(ca, arena);

  // K1: q = wq @ LN(cat1; an)
  gemm1x1_mfma<128, 128, 64, 1, true, false, false, 0, false>
      <<<dim3(HW_ / 64, 4), blk256, 0, stream>>>(f1c, f2c, wq, bq, an_g, an_b, 1e-6f,
                                                 nullptr, nullptr, qb, 0);
  // K2: kv = wkv @ LN(cat2; anc)
  gemm1x1_mfma<128, 256, 64, 1, true, false, false, 0, false>
      <<<dim3(HW_ / 64, 4), blk256, 0, stream>>>(f2c, f1c, wkv, bkv, anc_g, anc_b, 1e-6f,
                                                 nullptr, nullptr, kvb, 0);
  // K3: attention (MFMA)
  attn_mfma<<<dim3(64, 4, 4), blk256, 0, stream>>>(qb, kvb, obf);
  // K4: cat1r = wo @ o + bo + cat1(f32 originals)
  gemm1x1_mfma<128, 128, 64, 1, false, false, false, 4, true>
      <<<dim3(HW_ / 64, 4), blk256, 0, stream>>>(obf, nullptr, wo, bo, nullptr, nullptr, 0.f,
                                                 d_in[0], d_in[1], cat1r, 0);
  // K5: y = silu(w_in @ LN(cat1r; fn))
  gemm1x1_mfma<128, 256, 64, 1, true, true, true, 0, false>
      <<<dim3(HW_ / 64, 4), blk256, 0, stream>>>(cat1r, nullptr, w_in, b_in, fn_g, fn_b, 1e-5f,
                                                 nullptr, nullptr, yb, 0);
  // K6/K7 per batch (K7: POS=32 -> 50KB LDS, 512 blocks)
  for (int b = 0; b < 4; ++b) {
    dwconv_kernel<<<dim3(32, 256), blk256, 0, stream>>>(yb + (size_t)b * 256 * HW_,
                                                        w3, b3, w5, b5, w7, b7, fbuf_b);
    gemm1x1_mfma<768, 256, 32, 1, false, true, false, 2, false>
        <<<dim3(HW_ / 32, 1, 1), blk256, 0, stream>>>(fbuf_b, nullptr, w_pw, b_pw,
                                                      nullptr, nullptr, 0.f,
                                                      yb, nullptr, y2b, b);
  }
  // K8: out(f32) = cat1r + w_out @ y2 + b_out
  gemm1x1_mfma<256, 128, 64, 1, false, false, false, 3, true>
      <<<dim3(HW_ / 64, 4), blk256, 0, stream>>>(y2b, nullptr, w_out, b_out,
                                                 nullptr, nullptr, 0.f,
                                                 cat1r, nullptr, outp, 0);
}

// Round 9
// 432.579 us; speedup vs baseline: 1.1237x; 1.1237x over previous
//
#include <hip/hip_runtime.h>

typedef unsigned short u16;
typedef unsigned int u32;

constexpr int H_ = 64;
constexpr int W_ = 256;
constexpr int HW_ = H_ * W_;

typedef __bf16 bf16x8 __attribute__((ext_vector_type(8)));
typedef float f32x4 __attribute__((ext_vector_type(4)));

__device__ __forceinline__ float bf2f(u16 v) { return __uint_as_float(((u32)v) << 16); }
__device__ __forceinline__ u16 f2bf(float f) {
  u32 x = __float_as_uint(f);
  u32 r = (x + 0x7fffu + ((x >> 16) & 1u)) >> 16;
  return (u16)r;
}
__device__ __forceinline__ float lo2f(u32 p) { return __uint_as_float(p << 16); }
__device__ __forceinline__ float hi2f(u32 p) { return __uint_as_float(p & 0xffff0000u); }
__device__ __forceinline__ void unpack8(uint4 v, float* f) {
  f[0] = lo2f(v.x); f[1] = hi2f(v.x);
  f[2] = lo2f(v.y); f[3] = hi2f(v.y);
  f[4] = lo2f(v.z); f[5] = hi2f(v.z);
  f[6] = lo2f(v.w); f[7] = hi2f(v.w);
}
__device__ __forceinline__ bf16x8 as_bf16x8(uint4 v) {
  union { uint4 u; bf16x8 b; } x; x.u = v; return x.b;
}
__device__ __forceinline__ int swz(int p, int c) { return c ^ (((p >> 3) & 3) << 3); }

// ---------------- normalize all f32 inputs to a bf16 arena ----------------
constexpr int NT = 26;
constexpr int ELEMS_PER_BLK = 4096;
struct CvtArgs {
  const void* src[NT];
  u32 dst_off[NT];
  u32 n[NT];
  u32 blk_start[NT];
};

__global__ void convert_all(CvtArgs a, u16* __restrict__ dst) {
  const u32 bid = blockIdx.x;
  int ti = 0;
#pragma unroll
  for (int k = 1; k < NT; ++k) if (a.blk_start[k] <= bid) ti = k;
  const u32 e0 = (bid - a.blk_start[ti]) * ELEMS_PER_BLK;
  const u32 n = a.n[ti];
  u32 hi = e0 + ELEMS_PER_BLK; if (hi > n) hi = n;
  const float* sp = (const float*)a.src[ti];
  u16* d = dst + a.dst_off[ti];
  for (u32 i = e0 + threadIdx.x; i < hi; i += 256) d[i] = f2bf(sp[i]);
}

// ---------------- MFMA 1x1-conv GEMM with LN (K1/K2 only) ----------------
template <int CIN, int COUT>
__launch_bounds__(256)
__global__ void gemm1x1_ln(const u16* __restrict__ xA, const u16* __restrict__ xB,
                           const u16* __restrict__ w, const u16* __restrict__ bias,
                           const u16* __restrict__ lng, const u16* __restrict__ lnb,
                           float lneps, u16* __restrict__ out) {
  constexpr int POS = 64;
  constexpr int PITCH = CIN + 8;
  constexpr int MT = COUT / 64;
  __shared__ __align__(16) u16 xs[POS * PITCH];
  __shared__ float red1[256], red2[256], stm[64], str[64];
  const int t = threadIdx.x;
  const int b = blockIdx.y;
  const int pos0 = blockIdx.x * POS;

  const u16* basep = (b >= 2) ? xB : xA;
  const int bb = (b < 2) ? b : b - 2;
  const u16* xb16 = basep + (size_t)bb * CIN * HW_;

  constexpr int NLOAD = CIN * POS / 8;
  for (int idx = t; idx < NLOAD; idx += 256) {
    const int c = idx / (POS / 8);
    const int p8 = (idx % (POS / 8)) * 8;
    uint4 v = *(const uint4*)(xb16 + (size_t)c * HW_ + pos0 + p8);
    const int csw = swz(p8, c);
    u16* row = xs + p8 * PITCH + csw;
    row[0]         = (u16)v.x; row[PITCH]     = (u16)(v.x >> 16);
    row[2 * PITCH] = (u16)v.y; row[3 * PITCH] = (u16)(v.y >> 16);
    row[4 * PITCH] = (u16)v.z; row[5 * PITCH] = (u16)(v.z >> 16);
    row[6 * PITCH] = (u16)v.w; row[7 * PITCH] = (u16)(v.w >> 16);
  }
  __syncthreads();

  {  // LN over channels (CIN=128)
    const int p = t & 63, part = t >> 6;
    const int xorp = ((p >> 3) & 3) << 3;
    float s = 0.f, sq = 0.f;
#pragma unroll
    for (int k = 0; k < 32; k += 8) {
      uint4 v = *(const uint4*)(xs + p * PITCH + ((part * 32 + k) ^ xorp));
      float f[8]; unpack8(v, f);
#pragma unroll
      for (int j = 0; j < 8; ++j) { s += f[j]; sq += f[j] * f[j]; }
    }
    red1[part * 64 + p] = s; red2[part * 64 + p] = sq;
    __syncthreads();
    if (t < 64) {
      float ss = red1[t] + red1[64 + t] + red1[128 + t] + red1[192 + t];
      float qq = red2[t] + red2[64 + t] + red2[128 + t] + red2[192 + t];
      float m = ss * (1.0f / CIN);
      float var = qq * (1.0f / CIN) - m * m;
      var = var < 0.f ? 0.f : var;
      stm[t] = m; str[t] = rsqrtf(var + lneps);
    }
    __syncthreads();
    const float m = stm[p], r = str[p];
#pragma unroll
    for (int k = 0; k < 32; k += 8) {
      const int c = part * 32 + k;
      uint4 v = *(const uint4*)(xs + p * PITCH + (c ^ xorp));
      float f[8]; unpack8(v, f);
      u32 pk[4];
#pragma unroll
      for (int j = 0; j < 8; j += 2) {
        float g0 = bf2f(lng[c + j]), be0 = bf2f(lnb[c + j]);
        float g1 = bf2f(lng[c + j + 1]), be1 = bf2f(lnb[c + j + 1]);
        u16 lo = f2bf((f[j] - m) * r * g0 + be0);
        u16 hi = f2bf((f[j + 1] - m) * r * g1 + be1);
        pk[j >> 1] = (u32)lo | ((u32)hi << 16);
      }
      uint4 ov; ov.x = pk[0]; ov.y = pk[1]; ov.z = pk[2]; ov.w = pk[3];
      *(uint4*)(xs + p * PITCH + (c ^ xorp)) = ov;
    }
    __syncthreads();
  }

  const int lane = t & 63, wv = t >> 6;
  const int lo16 = lane & 15, quad = lane >> 4;
  const int orow0 = wv * MT * 16;
  const int qrow = quad * 4;

  f32x4 acc[MT][4];
#pragma unroll
  for (int mt = 0; mt < MT; ++mt) {
#pragma unroll
    for (int r = 0; r < 4; ++r) {
      const float bv = bf2f(bias[orow0 + mt * 16 + qrow + r]);
#pragma unroll
      for (int nt = 0; nt < 4; ++nt) acc[mt][nt][r] = bv;
    }
  }

  const u16* xb[4];
#pragma unroll
  for (int nt = 0; nt < 4; ++nt) {
    const int row = nt * 16 + lo16;
    xb[nt] = xs + row * PITCH + (quad * 8 ^ ((((row >> 3) & 3)) << 3));
  }
  const u16* wl = w + (size_t)(orow0 + lo16) * CIN + quad * 8;

#pragma unroll 2
  for (int kc = 0; kc < CIN / 32; ++kc) {
    const int c0 = kc * 32;
    bf16x8 bfr[4];
#pragma unroll
    for (int nt = 0; nt < 4; ++nt)
      bfr[nt] = as_bf16x8(*(const uint4*)(xb[nt] + c0));
#pragma unroll
    for (int mt = 0; mt < MT; ++mt) {
      bf16x8 afr = as_bf16x8(*(const uint4*)(wl + (size_t)mt * 16 * CIN + c0));
#pragma unroll
      for (int nt = 0; nt < 4; ++nt)
        acc[mt][nt] = __builtin_amdgcn_mfma_f32_16x16x32_bf16(afr, bfr[nt], acc[mt][nt], 0, 0, 0);
    }
  }

#pragma unroll
  for (int mt = 0; mt < MT; ++mt) {
#pragma unroll
    for (int nt = 0; nt < 4; ++nt) {
#pragma unroll
      for (int r = 0; r < 4; ++r) {
        const int o = orow0 + mt * 16 + qrow + r;
        const int p = pos0 + nt * 16 + lo16;
        out[((size_t)b * COUT + o) * HW_ + p] = f2bf(acc[mt][nt][r]);
      }
    }
  }
}

// ---------------- MFMA attention ----------------
__launch_bounds__(256)
__global__ void attn_mfma(const u16* __restrict__ qb, const u16* __restrict__ kvb,
                          u16* __restrict__ ob) {
  constexpr int PA = 40;
  constexpr int PJ = 264;
  __shared__ __align__(16) u16 kT[256 * PA];
  __shared__ __align__(16) u16 vT[32 * PJ];
  __shared__ __align__(16) u16 PlO[4 * 16 * PJ];
  const int t = threadIdx.x;
  const int h = blockIdx.x, n = blockIdx.y, b = blockIdx.z;
  const size_t qbase = ((size_t)(b * 128 + n * 32)) * HW_ + (size_t)h * W_;
  const size_t kbase = ((size_t)(b * 256 + n * 32)) * HW_ + (size_t)h * W_;
  const size_t vbase = ((size_t)(b * 256 + 128 + n * 32)) * HW_ + (size_t)h * W_;

#pragma unroll
  for (int d8 = 0; d8 < 4; ++d8) {
    u32 pk[4];
#pragma unroll
    for (int j = 0; j < 4; ++j) {
      u32 lo = kvb[kbase + (size_t)(d8 * 8 + 2 * j) * HW_ + t];
      u32 hi = kvb[kbase + (size_t)(d8 * 8 + 2 * j + 1) * HW_ + t];
      pk[j] = lo | (hi << 16);
    }
    *(uint4*)(kT + t * PA + d8 * 8) = make_uint4(pk[0], pk[1], pk[2], pk[3]);
  }
#pragma unroll
  for (int k = 0; k < 16; ++k) {
    const int idx = k * 256 + t;
    const int d = idx >> 7, p2 = (idx & 127) * 2;
    u32 v = *(const u32*)(kvb + vbase + (size_t)d * HW_ + p2);
    *(u32*)(vT + d * PJ + p2) = v;
  }
  __syncthreads();

  const int lane = t & 63, wv = t >> 6;
  const int lo16 = lane & 15, quad = lane >> 4;
  const float scale = 0.17677669529663687f;
  const float renorm = 1.0f / (1.0f + 256.0f * 1e-6f);
  const float addc = 1e-6f * renorm;
  u16* Pw = PlO + wv * 16 * PJ;

  f32x4 oacc[4][2];
  for (int ii = 0; ii < 4; ++ii) {
    const int i0 = ii * 64 + wv * 16;
    u16 qr[8];
#pragma unroll
    for (int j = 0; j < 8; ++j)
      qr[j] = qb[qbase + (size_t)(quad * 8 + j) * HW_ + i0 + lo16];
    bf16x8 qa;
#pragma unroll
    for (int j = 0; j < 8; ++j) qa[j] = *(__bf16*)&qr[j];
    f32x4 s[16];
#pragma unroll
    for (int jt = 0; jt < 16; ++jt) {
      bf16x8 kb = as_bf16x8(*(const uint4*)(kT + (jt * 16 + lo16) * PA + quad * 8));
      f32x4 z = {0.f, 0.f, 0.f, 0.f};
      s[jt] = __builtin_amdgcn_mfma_f32_16x16x32_bf16(qa, kb, z, 0, 0, 0);
    }
#pragma unroll
    for (int r = 0; r < 4; ++r) {
      float sum = 0.f;
#pragma unroll
      for (int jt = 0; jt < 16; ++jt) {
        float e = __expf(s[jt][r] * scale);
        s[jt][r] = e; sum += e;
      }
#pragma unroll
      for (int off = 1; off <= 8; off <<= 1) sum += __shfl_xor(sum, off, 64);
      const float inv2 = renorm / sum;
#pragma unroll
      for (int jt = 0; jt < 16; ++jt)
        Pw[(quad * 4 + r) * PJ + jt * 16 + lo16] = f2bf(fmaf(s[jt][r], inv2, addc));
    }
    f32x4 o0 = {0.f, 0.f, 0.f, 0.f}, o1 = {0.f, 0.f, 0.f, 0.f};
#pragma unroll
    for (int kt = 0; kt < 8; ++kt) {
      bf16x8 pa = as_bf16x8(*(const uint4*)(Pw + lo16 * PJ + kt * 32 + quad * 8));
      bf16x8 v0 = as_bf16x8(*(const uint4*)(vT + lo16 * PJ + kt * 32 + quad * 8));
      bf16x8 v1 = as_bf16x8(*(const uint4*)(vT + (16 + lo16) * PJ + kt * 32 + quad * 8));
      o0 = __builtin_amdgcn_mfma_f32_16x16x32_bf16(pa, v0, o0, 0, 0, 0);
      o1 = __builtin_amdgcn_mfma_f32_16x16x32_bf16(pa, v1, o1, 0, 0, 0);
    }
    oacc[ii][0] = o0; oacc[ii][1] = o1;
  }
  __syncthreads();
  u16* Ob = PlO;
#pragma unroll
  for (int ii = 0; ii < 4; ++ii) {
    const int i0 = ii * 64 + wv * 16;
#pragma unroll
    for (int r = 0; r < 4; ++r) {
      Ob[(i0 + quad * 4 + r) * PA + lo16] = f2bf(oacc[ii][0][r]);
      Ob[(i0 + quad * 4 + r) * PA + 16 + lo16] = f2bf(oacc[ii][1][r]);
    }
  }
  __syncthreads();
  for (int d = 0; d < 32; ++d) ob[qbase + (size_t)d * HW_ + t] = Ob[t * PA + d];
}

// ---------------- fused K4+K5: o-proj + residual -> cat1b, LN, w_in + SiLU -> yb --------
__launch_bounds__(256)
__global__ void fused_proj_ffn(const u16* __restrict__ obf,
                               const u16* __restrict__ wo, const u16* __restrict__ bo_,
                               const float* __restrict__ f1, const float* __restrict__ f2,
                               const u16* __restrict__ fng, const u16* __restrict__ fnb,
                               const u16* __restrict__ w_in, const u16* __restrict__ b_in,
                               u16* __restrict__ cat1b, u16* __restrict__ yb) {
  constexpr int PITCH = 136;
  __shared__ __align__(16) u16 xs[64 * PITCH];
  __shared__ float red1[256], red2[256], stm[64], str[64];
  const int t = threadIdx.x;
  const int b = blockIdx.y;
  const int pos0 = blockIdx.x * 64;
  const u16* xb16 = obf + (size_t)b * 128 * HW_;

  for (int idx = t; idx < 1024; idx += 256) {
    const int c = idx >> 3, p8 = (idx & 7) * 8;
    uint4 v = *(const uint4*)(xb16 + (size_t)c * HW_ + pos0 + p8);
    const int csw = swz(p8, c);
    u16* row = xs + p8 * PITCH + csw;
    row[0]         = (u16)v.x; row[PITCH]     = (u16)(v.x >> 16);
    row[2 * PITCH] = (u16)v.y; row[3 * PITCH] = (u16)(v.y >> 16);
    row[4 * PITCH] = (u16)v.z; row[5 * PITCH] = (u16)(v.z >> 16);
    row[6 * PITCH] = (u16)v.w; row[7 * PITCH] = (u16)(v.w >> 16);
  }
  __syncthreads();

  const int lane = t & 63, wv = t >> 6;
  const int lo16 = lane & 15, quad = lane >> 4, qrow = quad * 4;
  const u16* xb[4];
#pragma unroll
  for (int nt = 0; nt < 4; ++nt) {
    const int row = nt * 16 + lo16;
    xb[nt] = xs + row * PITCH + (quad * 8 ^ ((((row >> 3) & 3)) << 3));
  }

  // GEMM1: wo (128->128), MT=2
  const int orow0 = wv * 32;
  f32x4 acc1[2][4];
#pragma unroll
  for (int mt = 0; mt < 2; ++mt)
#pragma unroll
    for (int r = 0; r < 4; ++r) {
      const float bv = bf2f(bo_[orow0 + mt * 16 + qrow + r]);
#pragma unroll
      for (int nt = 0; nt < 4; ++nt) acc1[mt][nt][r] = bv;
    }
  const u16* wl1 = wo + (size_t)(orow0 + lo16) * 128 + quad * 8;
#pragma unroll
  for (int kc = 0; kc < 4; ++kc) {
    const int c0 = kc * 32;
    bf16x8 bfr[4];
#pragma unroll
    for (int nt = 0; nt < 4; ++nt) bfr[nt] = as_bf16x8(*(const uint4*)(xb[nt] + c0));
#pragma unroll
    for (int mt = 0; mt < 2; ++mt) {
      bf16x8 afr = as_bf16x8(*(const uint4*)(wl1 + (size_t)mt * 16 * 128 + c0));
#pragma unroll
      for (int nt = 0; nt < 4; ++nt)
        acc1[mt][nt] = __builtin_amdgcn_mfma_f32_16x16x32_bf16(afr, bfr[nt], acc1[mt][nt], 0, 0, 0);
    }
  }
  __syncthreads();   // all waves done reading xs

  // epilogue1: +cat1 (f32 originals), write cat1b global + xs (re-staged)
  {
    const int bl = (b < 2) ? b : b - 2;
    const float* rb = (b < 2) ? f1 : f2;
#pragma unroll
    for (int mt = 0; mt < 2; ++mt)
#pragma unroll
      for (int nt = 0; nt < 4; ++nt)
#pragma unroll
        for (int r = 0; r < 4; ++r) {
          const int o = orow0 + mt * 16 + qrow + r;
          const int p = nt * 16 + lo16;
          float v = acc1[mt][nt][r] + rb[((size_t)bl * 128 + o) * HW_ + pos0 + p];
          const u16 bv = f2bf(v);
          cat1b[((size_t)b * 128 + o) * HW_ + pos0 + p] = bv;
          xs[p * PITCH + swz(p, o)] = bv;
        }
  }
  __syncthreads();

  {  // LN (fn, eps 1e-5)
    const int p = t & 63, part = t >> 6;
    const int xorp = ((p >> 3) & 3) << 3;
    float s = 0.f, sq = 0.f;
#pragma unroll
    for (int k = 0; k < 32; k += 8) {
      uint4 v = *(const uint4*)(xs + p * PITCH + ((part * 32 + k) ^ xorp));
      float f[8]; unpack8(v, f);
#pragma unroll
      for (int j = 0; j < 8; ++j) { s += f[j]; sq += f[j] * f[j]; }
    }
    red1[part * 64 + p] = s; red2[part * 64 + p] = sq;
    __syncthreads();
    if (t < 64) {
      float ss = red1[t] + red1[64 + t] + red1[128 + t] + red1[192 + t];
      float qq = red2[t] + red2[64 + t] + red2[128 + t] + red2[192 + t];
      float m = ss * (1.0f / 128.0f);
      float var = qq * (1.0f / 128.0f) - m * m;
      var = var < 0.f ? 0.f : var;
      stm[t] = m; str[t] = rsqrtf(var + 1e-5f);
    }
    __syncthreads();
    const float m = stm[p], r = str[p];
#pragma unroll
    for (int k = 0; k < 32; k += 8) {
      const int c = part * 32 + k;
      uint4 v = *(const uint4*)(xs + p * PITCH + (c ^ xorp));
      float f[8]; unpack8(v, f);
      u32 pk[4];
#pragma unroll
      for (int j = 0; j < 8; j += 2) {
        float g0 = bf2f(fng[c + j]), be0 = bf2f(fnb[c + j]);
        float g1 = bf2f(fng[c + j + 1]), be1 = bf2f(fnb[c + j + 1]);
        u16 lo = f2bf((f[j] - m) * r * g0 + be0);
        u16 hi = f2bf((f[j + 1] - m) * r * g1 + be1);
        pk[j >> 1] = (u32)lo | ((u32)hi << 16);
      }
      uint4 ov; ov.x = pk[0]; ov.y = pk[1]; ov.z = pk[2]; ov.w = pk[3];
      *(uint4*)(xs + p * PITCH + (c ^ xorp)) = ov;
    }
    __syncthreads();
  }

  // GEMM2: w_in (128->256), MT=4, SiLU -> yb
  const int orow2 = wv * 64;
  f32x4 acc2[4][4];
#pragma unroll
  for (int mt = 0; mt < 4; ++mt)
#pragma unroll
    for (int r = 0; r < 4; ++r) {
      const float bv = bf2f(b_in[orow2 + mt * 16 + qrow + r]);
#pragma unroll
      for (int nt = 0; nt < 4; ++nt) acc2[mt][nt][r] = bv;
    }
  const u16* wl2 = w_in + (size_t)(orow2 + lo16) * 128 + quad * 8;
#pragma unroll
  for (int kc = 0; kc < 4; ++kc) {
    const int c0 = kc * 32;
    bf16x8 bfr[4];
#pragma unroll
    for (int nt = 0; nt < 4; ++nt) bfr[nt] = as_bf16x8(*(const uint4*)(xb[nt] + c0));
#pragma unroll
    for (int mt = 0; mt < 4; ++mt) {
      bf16x8 afr = as_bf16x8(*(const uint4*)(wl2 + (size_t)mt * 16 * 128 + c0));
#pragma unroll
      for (int nt = 0; nt < 4; ++nt)
        acc2[mt][nt] = __builtin_amdgcn_mfma_f32_16x16x32_bf16(afr, bfr[nt], acc2[mt][nt], 0, 0, 0);
    }
  }
#pragma unroll
  for (int mt = 0; mt < 4; ++mt)
#pragma unroll
    for (int nt = 0; nt < 4; ++nt)
#pragma unroll
      for (int r = 0; r < 4; ++r) {
        const int o = orow2 + mt * 16 + qrow + r;
        const int p = nt * 16 + lo16;
        float v = acc2[mt][nt][r];
        v = v / (1.0f + __expf(-v));
        yb[((size_t)b * 256 + o) * HW_ + pos0 + p] = f2bf(v);
      }
}

// ---------------- fused K7+K8: w_pw+SiLU+y-res -> y2(LDS) -> w_out + cat1b -> out ------
__launch_bounds__(256)
__global__ void fused_pw_out(const u16* __restrict__ fbase, size_t f_stride,
                             const u16* __restrict__ w_pw, const u16* __restrict__ b_pw,
                             const u16* __restrict__ yb,
                             const u16* __restrict__ w_out, const u16* __restrict__ b_out,
                             const u16* __restrict__ cat1b, float* __restrict__ outp,
                             int b_off) {
  constexpr int P1 = 776, P2 = 264;
  __shared__ __align__(16) u16 buf[64 * P1];   // 99.3 KB; reused as y2 (P2) later
  const int t = threadIdx.x;
  const int bo2 = (int)blockIdx.y + b_off;
  const int pos0 = blockIdx.x * 64;
  const u16* xf = fbase + (size_t)blockIdx.y * f_stride;

  for (int idx = t; idx < 6144; idx += 256) {
    const int c = idx >> 3, p8 = (idx & 7) * 8;
    uint4 v = *(const uint4*)(xf + (size_t)c * HW_ + pos0 + p8);
    const int csw = swz(p8, c);
    u16* row = buf + p8 * P1 + csw;
    row[0]      = (u16)v.x; row[P1]     = (u16)(v.x >> 16);
    row[2 * P1] = (u16)v.y; row[3 * P1] = (u16)(v.y >> 16);
    row[4 * P1] = (u16)v.z; row[5 * P1] = (u16)(v.z >> 16);
    row[6 * P1] = (u16)v.w; row[7 * P1] = (u16)(v.w >> 16);
  }
  __syncthreads();

  const int lane = t & 63, wv = t >> 6;
  const int lo16 = lane & 15, quad = lane >> 4, qrow = quad * 4;

  // GEMM1: w_pw (768->256), MT=4
  const u16* xb1[4];
#pragma unroll
  for (int nt = 0; nt < 4; ++nt) {
    const int row = nt * 16 + lo16;
    xb1[nt] = buf + row * P1 + (quad * 8 ^ ((((row >> 3) & 3)) << 3));
  }
  const int orow1 = wv * 64;
  f32x4 acc[4][4];
#pragma unroll
  for (int mt = 0; mt < 4; ++mt)
#pragma unroll
    for (int r = 0; r < 4; ++r) {
      const float bv = bf2f(b_pw[orow1 + mt * 16 + qrow + r]);
#pragma unroll
      for (int nt = 0; nt < 4; ++nt) acc[mt][nt][r] = bv;
    }
  const u16* wl1 = w_pw + (size_t)(orow1 + lo16) * 768 + quad * 8;
#pragma unroll 2
  for (int kc = 0; kc < 24; ++kc) {
    const int c0 = kc * 32;
    bf16x8 bfr[4];
#pragma unroll
    for (int nt = 0; nt < 4; ++nt) bfr[nt] = as_bf16x8(*(const uint4*)(xb1[nt] + c0));
#pragma unroll
    for (int mt = 0; mt < 4; ++mt) {
      bf16x8 afr = as_bf16x8(*(const uint4*)(wl1 + (size_t)mt * 16 * 768 + c0));
#pragma unroll
      for (int nt = 0; nt < 4; ++nt)
        acc[mt][nt] = __builtin_amdgcn_mfma_f32_16x16x32_bf16(afr, bfr[nt], acc[mt][nt], 0, 0, 0);
    }
  }
  __syncthreads();

  // epilogue1: SiLU + y residual -> buf as y2[p][c] (pitch P2)
#pragma unroll
  for (int mt = 0; mt < 4; ++mt)
#pragma unroll
    for (int nt = 0; nt < 4; ++nt)
#pragma unroll
      for (int r = 0; r < 4; ++r) {
        const int o = orow1 + mt * 16 + qrow + r;
        const int p = nt * 16 + lo16;
        float v = acc[mt][nt][r];
        v = v / (1.0f + __expf(-v));
        v += bf2f(yb[((size_t)bo2 * 256 + o) * HW_ + pos0 + p]);
        buf[p * P2 + swz(p, o)] = f2bf(v);
      }
  __syncthreads();

  // GEMM2: w_out (256->128), MT=2
  const u16* xb2[4];
#pragma unroll
  for (int nt = 0; nt < 4; ++nt) {
    const int row = nt * 16 + lo16;
    xb2[nt] = buf + row * P2 + (quad * 8 ^ ((((row >> 3) & 3)) << 3));
  }
  const int orow2 = wv * 32;
  f32x4 acc2[2][4];
#pragma unroll
  for (int mt = 0; mt < 2; ++mt)
#pragma unroll
    for (int r = 0; r < 4; ++r) {
      const float bv = bf2f(b_out[orow2 + mt * 16 + qrow + r]);
#pragma unroll
      for (int nt = 0; nt < 4; ++nt) acc2[mt][nt][r] = bv;
    }
  const u16* wl2 = w_out + (size_t)(orow2 + lo16) * 256 + quad * 8;
#pragma unroll
  for (int kc = 0; kc < 8; ++kc) {
    const int c0 = kc * 32;
    bf16x8 bfr[4];
#pragma unroll
    for (int nt = 0; nt < 4; ++nt) bfr[nt] = as_bf16x8(*(const uint4*)(xb2[nt] + c0));
#pragma unroll
    for (int mt = 0; mt < 2; ++mt) {
      bf16x8 afr = as_bf16x8(*(const uint4*)(wl2 + (size_t)mt * 16 * 256 + c0));
#pragma unroll
      for (int nt = 0; nt < 4; ++nt)
        acc2[mt][nt] = __builtin_amdgcn_mfma_f32_16x16x32_bf16(afr, bfr[nt], acc2[mt][nt], 0, 0, 0);
    }
  }
#pragma unroll
  for (int mt = 0; mt < 2; ++mt)
#pragma unroll
    for (int nt = 0; nt < 4; ++nt)
#pragma unroll
      for (int r = 0; r < 4; ++r) {
        const int o = orow2 + mt * 16 + qrow + r;
        const int p = nt * 16 + lo16;
        const size_t gidx = ((size_t)bo2 * 128 + o) * HW_ + pos0 + p;
        outp[gidx] = acc2[mt][nt][r] + bf2f(cat1b[gidx]);
      }
}

// ---------------- fused depthwise 3/5/7 (z = batch) ----------------
__launch_bounds__(256)
__global__ void dwconv_kernel(const u16* __restrict__ yB,
                              const u16* __restrict__ w3, const u16* __restrict__ b3,
                              const u16* __restrict__ w5, const u16* __restrict__ b5,
                              const u16* __restrict__ w7, const u16* __restrict__ b7,
                              u16* __restrict__ fB) {
  constexpr int LW = 70, LH = 14, LP = 72;
  __shared__ u16 tile[LH * LP];
  __shared__ float wf7[49], wf5[25], wf3[9];
  const int t = threadIdx.x;
  const int c = blockIdx.y;
  const int bz = blockIdx.z;
  const int tw = blockIdx.x & 3, th = blockIdx.x >> 2;
  const int w0 = tw * 64, h0 = th * 8;
  const u16* src = yB + ((size_t)bz * 256 + c) * HW_;

  if (t < 49) wf7[t] = bf2f(w7[c * 49 + t]);
  if (t >= 64 && t < 89) wf5[t - 64] = bf2f(w5[c * 25 + (t - 64)]);
  if (t >= 96 && t < 105) wf3[t - 96] = bf2f(w3[c * 9 + (t - 96)]);

  for (int idx = t; idx < LH * LW; idx += 256) {
    const int r = idx / LW, cc = idx - r * LW;
    const int gh = h0 + r - 3, gw = w0 + cc - 3;
    u16 v = 0;
    if (gh >= 0 && gh < H_ && gw >= 0 && gw < W_) v = src[gh * W_ + gw];
    tile[r * LP + cc] = v;
  }
  __syncthreads();

  const int x0 = (t & 31) * 2;
  const int hh = t >> 5;
  float a3x = 0.f, a3y = 0.f, a5x = 0.f, a5y = 0.f, a7x = 0.f, a7y = 0.f;
#pragma unroll
  for (int rr = 0; rr < 7; ++rr) {
    const u16* trow = tile + (hh + rr) * LP + x0;
    float f[10];
#pragma unroll
    for (int k = 0; k < 5; ++k) {
      u32 v = *(const u32*)(trow + 2 * k);
      f[2 * k] = lo2f(v); f[2 * k + 1] = hi2f(v);
    }
#pragma unroll
    for (int dx = 0; dx < 7; ++dx) {
      const float wv = wf7[rr * 7 + dx];
      a7x += wv * f[dx]; a7y += wv * f[dx + 1];
    }
    if (rr >= 1 && rr <= 5) {
#pragma unroll
      for (int dx = 0; dx < 5; ++dx) {
        const float wv = wf5[(rr - 1) * 5 + dx];
        a5x += wv * f[dx + 1]; a5y += wv * f[dx + 2];
      }
    }
    if (rr >= 2 && rr <= 4) {
#pragma unroll
      for (int dx = 0; dx < 3; ++dx) {
        const float wv = wf3[(rr - 2) * 3 + dx];
        a3x += wv * f[dx + 2]; a3y += wv * f[dx + 3];
      }
    }
  }
  const float B3v = bf2f(b3[c]), B5v = bf2f(b5[c]), B7v = bf2f(b7[c]);
  const size_t o0 = (size_t)bz * 768 * HW_ + (size_t)c * HW_ + (size_t)(h0 + hh) * W_ + (w0 + x0);
  *(u32*)(fB + o0) = (u32)f2bf(a3x + B3v) | ((u32)f2bf(a3y + B3v) << 16);
  *(u32*)(fB + o0 + (size_t)256 * HW_) = (u32)f2bf(a5x + B5v) | ((u32)f2bf(a5y + B5v) << 16);
  *(u32*)(fB + o0 + (size_t)512 * HW_) = (u32)f2bf(a7x + B7v) | ((u32)f2bf(a7y + B7v) << 16);
}

extern "C" void kernel_launch(void* const* d_in, const int* in_sizes, int n_in,
                              void* d_out, int out_size, void* d_ws, size_t ws_size,
                              hipStream_t stream) {
  (void)out_size; (void)n_in;
  char* ws = (char*)d_ws;
  const size_t MB = 1ull << 20;

  u16* arena = (u16*)ws;
  CvtArgs ca;
  u32 off = 0, blk = 0;
  u32 aoff[NT];
  for (int i = 0; i < NT; ++i) {
    ca.src[i] = d_in[i];
    ca.n[i] = (u32)in_sizes[i];
    ca.dst_off[i] = off;
    aoff[i] = off;
    ca.blk_start[i] = blk;
    off += (ca.n[i] + 15u) & ~15u;
    blk += (ca.n[i] + ELEMS_PER_BLK - 1) / ELEMS_PER_BLK;
  }
  const u32 total_blocks = blk;

  const u16* f1c   = arena + aoff[0];
  const u16* f2c   = arena + aoff[1];
  const u16* an_g  = arena + aoff[2];
  const u16* an_b  = arena + aoff[3];
  const u16* anc_g = arena + aoff[4];
  const u16* anc_b = arena + aoff[5];
  const u16* wq    = arena + aoff[6];
  const u16* bq    = arena + aoff[7];
  const u16* wkv   = arena + aoff[8];
  const u16* bkv   = arena + aoff[9];
  const u16* wo    = arena + aoff[10];
  const u16* bo_   = arena + aoff[11];
  const u16* fn_g  = arena + aoff[12];
  const u16* fn_b  = arena + aoff[13];
  const u16* w_in  = arena + aoff[14];
  const u16* b_in  = arena + aoff[15];
  const u16* w3    = arena + aoff[16];
  const u16* b3    = arena + aoff[17];
  const u16* w5    = arena + aoff[18];
  const u16* b5    = arena + aoff[19];
  const u16* w7    = arena + aoff[20];
  const u16* b7    = arena + aoff[21];
  const u16* w_pw  = arena + aoff[22];
  const u16* b_pw  = arena + aoff[23];
  const u16* w_out = arena + aoff[24];
  const u16* b_out = arena + aoff[25];

  // layout (MB): arena[0,18) cat1b[18,34) qb[34,50) kvb[50,82) obf[82,98)
  //              yb[34,66) (overlays qb+kvb-lo after attn)
  //              fbuf: big [66,167) / small per-batch [66,92)
  u16* cat1b  = (u16*)(ws + 18 * MB);
  u16* qb     = (u16*)(ws + 34 * MB);
  u16* kvb    = (u16*)(ws + 50 * MB);
  u16* obf    = (u16*)(ws + 82 * MB);
  u16* yb     = (u16*)(ws + 34 * MB);
  u16* fbuf   = (u16*)(ws + 66 * MB);
  float* outp = (float*)d_out;
  const bool big = ws_size >= 168 * MB;

  dim3 blk256(256);
  convert_all<<<total_blocks, 256, 0, stream>>>(ca, arena);

  gemm1x1_ln<128, 128><<<dim3(HW_ / 64, 4), blk256, 0, stream>>>(
      f1c, f2c, wq, bq, an_g, an_b, 1e-6f, qb);
  gemm1x1_ln<128, 256><<<dim3(HW_ / 64, 4), blk256, 0, stream>>>(
      f2c, f1c, wkv, bkv, anc_g, anc_b, 1e-6f, kvb);
  attn_mfma<<<dim3(64, 4, 4), blk256, 0, stream>>>(qb, kvb, obf);
  fused_proj_ffn<<<dim3(HW_ / 64, 4), blk256, 0, stream>>>(
      obf, wo, bo_, (const float*)d_in[0], (const float*)d_in[1],
      fn_g, fn_b, w_in, b_in, cat1b, yb);
  if (big) {
    dwconv_kernel<<<dim3(32, 256, 4), blk256, 0, stream>>>(yb, w3, b3, w5, b5, w7, b7, fbuf);
    fused_pw_out<<<dim3(HW_ / 64, 4), blk256, 0, stream>>>(
        fbuf, (size_t)768 * HW_, w_pw, b_pw, yb, w_out, b_out, cat1b, outp, 0);
  } else {
    for (int b = 0; b < 4; ++b) {
      dwconv_kernel<<<dim3(32, 256, 1), blk256, 0, stream>>>(
          yb + (size_t)b * 256 * HW_, w3, b3, w5, b5, w7, b7, fbuf);
      fused_pw_out<<<dim3(HW_ / 64, 1), blk256, 0, stream>>>(
          fbuf, 0, w_pw, b_pw, yb, w_out, b_out, cat1b, outp, b);
    }
  }
}